// Round 1
// 820.396 us; speedup vs baseline: 1.0573x; 1.0573x over previous
//
#include <hip/hip_runtime.h>

#define N_DIM 32768
#define K_DIM 4096
#define D_DIM 512
#define NTILE 32                 // K_DIM / 128 column tiles

typedef __attribute__((ext_vector_type(8))) short short8;
typedef __attribute__((ext_vector_type(4))) float f32x4;

// ---------------------------------------------------------------- helpers

__device__ __forceinline__ unsigned short f32_to_bf16_rne(float f) {
  unsigned int u = __builtin_bit_cast(unsigned int, f);
  u += 0x7fffu + ((u >> 16) & 1u);   // round-to-nearest-even (inputs finite)
  return (unsigned short)(u >> 16);
}

__device__ __forceinline__ void gl2lds16(const void* g, void* l) {
  // async global->LDS, 16B per lane; LDS dest = wave-uniform base + lane*16
  __builtin_amdgcn_global_load_lds(
      (const __attribute__((address_space(1))) unsigned int*)g,
      (__attribute__((address_space(3))) unsigned int*)l, 16, 0, 0);
}

// ---------------------------------------------------------------- kernel 0/1: fp32 -> bf16

__global__ __launch_bounds__(256) void cvt_bf16(const float* __restrict__ in,
                                                unsigned short* __restrict__ out,
                                                int n4) {
  int i = blockIdx.x * 256 + threadIdx.x;
  if (i < n4) {
    float4 f = ((const float4*)in)[i];
    ushort4 u;
    u.x = f32_to_bf16_rne(f.x);
    u.y = f32_to_bf16_rne(f.y);
    u.z = f32_to_bf16_rne(f.z);
    u.w = f32_to_bf16_rne(f.w);
    ((ushort4*)out)[i] = u;
  }
}

// ---------------------------------------------------------------- kernel 2: bf16 MFMA GEMM (C = A * B^T) + fused per-row tile max
// A: [N][D] bf16, B: [K][D] bf16 (both row-major, shared inner dim D) -> C [N][K] fp32
// 128x128 tile, BK=32, 4 waves each computing a 64x64 quadrant via 4x4 of 16x16x32 MFMA.
// NEW: epilogue also emits Pmax[row][tile] = max over this block's 128 columns,
// so the argmax pass never has to re-read the 536 MB logits array.

__global__ __launch_bounds__(256) void gemm_bf16(const unsigned short* __restrict__ A,
                                                 const unsigned short* __restrict__ B,
                                                 float* __restrict__ C,
                                                 float* __restrict__ Pmax) {
  __shared__ __align__(16) short As[128 * 32];  // rows of 32 bf16 (64 B), no pad (global_load_lds layout)
  __shared__ __align__(16) short Bs[128 * 32];
  __shared__ float sMax[128][2];                // per-row quadrant maxes (wc = 0/1)

  const int tid = threadIdx.x;
  const int l   = tid & 63;
  const int w   = tid >> 6;        // wave 0..3
  const int wr  = w >> 1;          // quadrant row (0/1)
  const int wc  = w & 1;           // quadrant col (0/1)
  const int m   = l & 15;          // fragment row/col within 16
  const int q   = l >> 4;          // quad 0..3

  const int blockCol = blockIdx.x * 128;  // codes (K dim)
  const int blockRow = blockIdx.y * 128;  // z rows (N dim)

  // staging: 8 wave-loads of 1KB per operand; wave w does slots w and w+4.
  const int lrow   = l >> 2;        // 16 rows per 1KB slot
  const int lchunk = (l & 3) * 8;   // 4 chunks of 8 bf16 per 64B row
  const unsigned short* ga0 = A + (size_t)(blockRow + w * 16 + lrow) * D_DIM + lchunk;
  const unsigned short* ga1 = ga0 + (size_t)64 * D_DIM;
  const unsigned short* gb0 = B + (size_t)(blockCol + w * 16 + lrow) * D_DIM + lchunk;
  const unsigned short* gb1 = gb0 + (size_t)64 * D_DIM;
  short* la0 = As + w * 512;
  short* la1 = As + (w + 4) * 512;
  short* lb0 = Bs + w * 512;
  short* lb1 = Bs + (w + 4) * 512;

  f32x4 acc[4][4] = {};

  for (int k0 = 0; k0 < D_DIM; k0 += 32) {
    gl2lds16(ga0, la0);
    gl2lds16(ga1, la1);
    gl2lds16(gb0, lb0);
    gl2lds16(gb1, lb1);
    __syncthreads();   // barrier drains vmcnt -> LDS data visible

    short8 af[4], bfr[4];
#pragma unroll
    for (int mi = 0; mi < 4; mi++)
      af[mi] = *(const short8*)(As + (wr * 64 + mi * 16 + m) * 32 + q * 8);
#pragma unroll
    for (int ni = 0; ni < 4; ni++)
      bfr[ni] = *(const short8*)(Bs + (wc * 64 + ni * 16 + m) * 32 + q * 8);

#pragma unroll
    for (int mi = 0; mi < 4; mi++)
#pragma unroll
      for (int ni = 0; ni < 4; ni++)
        acc[mi][ni] = __builtin_amdgcn_mfma_f32_16x16x32_bf16(af[mi], bfr[ni], acc[mi][ni], 0, 0, 0);

    __syncthreads();   // protect LDS before next staging overwrite
    ga0 += 32; ga1 += 32; gb0 += 32; gb1 += 32;
  }

  // epilogue: C/D layout col = lane&15, row = quad*4 + reg  [m89/m91-verified]
#pragma unroll
  for (int mi = 0; mi < 4; mi++) {
#pragma unroll
    for (int r = 0; r < 4; r++) {
      const int row = blockRow + wr * 64 + mi * 16 + q * 4 + r;
      float* crow = C + (size_t)row * K_DIM + blockCol + wc * 64 + m;
#pragma unroll
      for (int ni = 0; ni < 4; ni++) crow[ni * 16] = acc[mi][ni][r];
    }
  }

  // fused per-row max over this wave's 64x64 quadrant.
  // For each fragment row (mi, r): the 64 columns live in 4 regs (ni) x 16 lanes
  // of this q-group -> local max over ni, then 4-step shfl_xor across the 16 lanes.
#pragma unroll
  for (int mi = 0; mi < 4; mi++) {
#pragma unroll
    for (int r = 0; r < 4; r++) {
      float vmax = fmaxf(fmaxf(acc[mi][0][r], acc[mi][1][r]),
                         fmaxf(acc[mi][2][r], acc[mi][3][r]));
#pragma unroll
      for (int off = 8; off >= 1; off >>= 1) vmax = fmaxf(vmax, __shfl_xor(vmax, off));
      if (m == 0) sMax[wr * 64 + mi * 16 + q * 4 + r][wc] = vmax;
    }
  }
  __syncthreads();
  if (tid < 128) {
    float rm = fmaxf(sMax[tid][0], sMax[tid][1]);
    Pmax[(size_t)(blockRow + tid) * NTILE + blockIdx.x] = rm;
  }
}

// ---------------------------------------------------------------- kernel 3: finalize argmax
// One WAVE per row (4 rows per 256-thr block). Reads the 32 tile maxes (128 B),
// reduces to the global row max, scans only candidate tiles (tile max within
// DELTA of global max -- usually exactly one, 512 B), then refines each
// candidate (~1.1 per row) with an exact fp64 dot from the fp32 inputs
// (64 lanes x 8 elems, float4 loads, shuffle reduce). Replaces the old
// argmax kernel's 536 MB full-logits re-read.

#define DELTA 6.0e-4f

__global__ __launch_bounds__(256) void finalize_argmax(const float* __restrict__ Pmax,
                                                       const float* __restrict__ C,
                                                       const float* __restrict__ Z,
                                                       const float* __restrict__ CB,
                                                       float* __restrict__ outIdx) {
  const int row  = blockIdx.x * 4 + (threadIdx.x >> 6);
  const int lane = threadIdx.x & 63;

  // global row max from the 32 tile maxes
  float pv = (lane < NTILE) ? Pmax[(size_t)row * NTILE + lane] : -3.0e38f;
  float gmax = pv;
#pragma unroll
  for (int off = 32; off >= 1; off >>= 1) gmax = fmaxf(gmax, __shfl_xor(gmax, off));
  const float th = gmax - DELTA;

  unsigned long long tmask = __ballot(lane < NTILE && pv >= th);

  // hoist the Z row (reused across all candidates)
  const float4* zr4 = (const float4*)(Z + (size_t)row * D_DIM);
  const float4 z0 = zr4[lane], z1 = zr4[lane + 64];

  double best = -1.0e300;
  int    bi   = 0x7fffffff;

  while (tmask) {
    const int t = __ffsll(tmask) - 1;
    tmask &= tmask - 1;
    // scan this tile's 128 logits (2 per lane)
    const float2 c2 = ((const float2*)(C + (size_t)row * K_DIM + t * 128))[lane];
    unsigned long long cm0 = __ballot(c2.x >= th);
    unsigned long long cm1 = __ballot(c2.y >= th);
    while (cm0 | cm1) {
      int k;
      if (cm0) { int b = __ffsll(cm0) - 1; cm0 &= cm0 - 1; k = t * 128 + 2 * b; }
      else     { int b = __ffsll(cm1) - 1; cm1 &= cm1 - 1; k = t * 128 + 2 * b + 1; }
      // exact fp64 dot, whole wave
      const float4* br4 = (const float4*)(CB + (size_t)k * D_DIM);
      float4 b0 = br4[lane], b1 = br4[lane + 64];
      double s = (double)z0.x * b0.x + (double)z0.y * b0.y +
                 (double)z0.z * b0.z + (double)z0.w * b0.w +
                 (double)z1.x * b1.x + (double)z1.y * b1.y +
                 (double)z1.z * b1.z + (double)z1.w * b1.w;
#pragma unroll
      for (int off = 32; off >= 1; off >>= 1) s += __shfl_xor(s, off);
      if (s > best || (s == best && k < bi)) { best = s; bi = k; }
    }
  }
  if (lane == 0) outIdx[row] = (float)bi;
}

// ---------------------------------------------------------------- launch

extern "C" void kernel_launch(void* const* d_in, const int* in_sizes, int n_in,
                              void* d_out, int out_size, void* d_ws, size_t ws_size,
                              hipStream_t stream) {
  const float* Z  = (const float*)d_in[0];   // [N][D] fp32
  const float* CB = (const float*)d_in[1];   // [K][D] fp32
  float* out = (float*)d_out;                // [N*K logits][N indices-as-float]

  unsigned short* Abf = (unsigned short*)d_ws;                              // 32 MiB
  unsigned short* Bbf = (unsigned short*)d_ws + (size_t)N_DIM * D_DIM;      // +4 MiB
  float* Pmax = (float*)(Bbf + (size_t)K_DIM * D_DIM);                      // +4 MiB (row tile maxes)

  cvt_bf16<<<(N_DIM * D_DIM / 4) / 256, 256, 0, stream>>>(Z, Abf, N_DIM * D_DIM / 4);
  cvt_bf16<<<(K_DIM * D_DIM / 4) / 256, 256, 0, stream>>>(CB, Bbf, K_DIM * D_DIM / 4);

  dim3 grid(K_DIM / 128, N_DIM / 128);
  gemm_bf16<<<grid, 256, 0, stream>>>(Abf, Bbf, out, Pmax);

  finalize_argmax<<<N_DIM / 4, 256, 0, stream>>>(Pmax, out, Z, CB,
                                                 out + (size_t)N_DIM * K_DIM);
}